// Round 7
// baseline (361.856 us; speedup 1.0000x reference)
//
#include <hip/hip_runtime.h>
#include <math.h>

// Problem constants (B, C, T, V, d_k) = (8, 256, 2048, 25, 64)
#define BB 8
#define CC 256
#define TT 2048
#define VV 25
#define DK 64
#define XPH 1048576   // B*T*DK u16 elements per KV-split quarter
#define MLQ 16384     // B*T floats (l only; max-free softmax) per quarter

typedef unsigned short u16;
typedef unsigned int u32;
typedef float f32x4 __attribute__((ext_vector_type(4)));
typedef short short8 __attribute__((ext_vector_type(8)));

__device__ __forceinline__ u16 f2bf(float x) {
    u32 u = __builtin_bit_cast(u32, x);
    u32 r = (u + 0x7FFFu + ((u >> 16) & 1u)) >> 16;   // RNE
    return (u16)r;
}
__device__ __forceinline__ u32 pk2(float a, float b) {
    return (u32)f2bf(a) | ((u32)f2bf(b) << 16);
}
// HW packed cvt (T12, m214v22): D.lo = bf16(S0), D.hi = bf16(S1), RNE
__device__ __forceinline__ u32 cvtpk(float a, float b) {
    u32 r;
    asm("v_cvt_pk_bf16_f32 %0, %1, %2" : "=v"(r) : "v"(a), "v"(b));
    return r;
}

// XOR swizzles (T2). Row-stride-128B tiles: swzA f(row)=row&7; swzB adds row>>3
// (for transpose-scatter writes). swzX: row-stride-512B tiles (row at bit 9).
__device__ __forceinline__ u32 swzA(u32 byte) {
    return byte ^ (((byte >> 7) & 7u) << 4);
}
__device__ __forceinline__ u32 swzB(u32 byte) {
    u32 row = byte >> 7;
    return byte ^ ((((row & 7u) ^ ((row >> 3) & 7u))) << 4);
}
__device__ __forceinline__ u32 swzX(u32 byte) {
    return byte ^ (((byte >> 9) & 7u) << 4);
}

// -------------------- K1: pool over V: x (B,C,T,V) -> p0 (B,C,T) bf16 ----------------
// 2048 blocks x 128 threads, grid-stride over 8 chunks. Double-buffered LDS:
// ONE barrier per chunk (write buf -> bar -> read buf; WAR covered by next bar).
__global__ __launch_bounds__(128) void pool_kernel(const float* __restrict__ x,
                                                   u16* __restrict__ p0) {
    __shared__ float lds[2][256 * VV];
    const int tid = threadIdx.x;
    int pb = 0;
    for (int u = blockIdx.x; u < 16384; u += 2048) {
        float* buf = lds[pb];
        const uint2* xu = (const uint2*)(x + (long long)u * (256LL * VV));
        #pragma unroll
        for (int j = 0; j < VV; ++j)
            *(uint2*)&buf[2 * (tid + 128 * j)] = xu[tid + 128 * j];
        __syncthreads();
        float s0 = 0.f, s1 = 0.f;
        #pragma unroll
        for (int j = 0; j < VV; ++j) {
            s0 += buf[50 * tid + j];          // stride 50: gcd(50,32)=2 -> 2-way, free
            s1 += buf[50 * tid + VV + j];
        }
        *(u32*)&p0[(long long)u * 256 + 2 * tid] = pk2(s0 * (1.0f / 25.0f),
                                                       s1 * (1.0f / 25.0f));
        pb ^= 1;
    }
}

// -------------------- K2: fused QKV GEMM: Qt/Kt/Vt (B,64,T) = W @ p0(B,C,T) ----------
// 256 blocks = 8b x 32 t-chunks(64). p0 is bf16 now: stage = bit-merge only.
// Q pre-scaled by (1/8)*log2(e) so flash softmax uses bare exp2.
__global__ __launch_bounds__(256) void qkv_gemm(
    const u16* __restrict__ p0, const float* __restrict__ Wq,
    const float* __restrict__ Wk, const float* __restrict__ Wv,
    u16* __restrict__ QT, u16* __restrict__ KT, u16* __restrict__ VT)
{
    __shared__ u16 xlds[64 * 256];       // [t][c], swzX
    const int tid = threadIdx.x;
    const int lane = tid & 63, w = tid >> 6, g = lane >> 4, q15 = lane & 15;
    const int b = blockIdx.x >> 5, t0 = (blockIdx.x & 31) * 64;
    const u16* p0b = p0 + (size_t)b * (CC * TT);

    // stage x_t^T tile (bf16 in, [t][c] packed pairs out)
    const int c0 = (tid & 127) * 2, th = tid >> 7;
    char* xl = (char*)xlds;
    {
        const u16* r0p = p0b + (size_t)c0 * TT + t0 + th * 32;
        const u16* r1p = r0p + TT;
        #pragma unroll
        for (int j = 0; j < 4; ++j) {
            uint4 a = ((const uint4*)r0p)[j];    // 8 t's of row c0
            uint4 bq = ((const uint4*)r1p)[j];   // 8 t's of row c0+1
            u32 av[4] = {a.x, a.y, a.z, a.w};
            u32 bv[4] = {bq.x, bq.y, bq.z, bq.w};
            #pragma unroll
            for (int e = 0; e < 4; ++e) {
                int tb = th * 32 + j * 8 + e * 2;
                u32 w0 = (av[e] & 0xFFFFu) | (bv[e] << 16);
                u32 w1 = (av[e] >> 16) | (bv[e] & 0xFFFF0000u);
                *(u32*)(xl + swzX((u32)(tb * 512 + c0 * 2)))       = w0;
                *(u32*)(xl + swzX((u32)((tb + 1) * 512 + c0 * 2))) = w1;
            }
        }
    }
    short8 af[3][8];
    const float* Wmats[3] = {Wq, Wk, Wv};
    #pragma unroll
    for (int m = 0; m < 3; ++m) {
        const float* wr = Wmats[m] + (16 * w + q15) * 256 + 8 * g;
        const float scale = (m == 0) ? 0.125f * 1.44269504089f : 1.0f;  // fold log2(e)
        #pragma unroll
        for (int kw = 0; kw < 8; ++kw) {
            float4 a = *(const float4*)(wr + kw * 32);
            float4 c = *(const float4*)(wr + kw * 32 + 4);
            short8 s;
            s[0] = (short)f2bf(a.x * scale); s[1] = (short)f2bf(a.y * scale);
            s[2] = (short)f2bf(a.z * scale); s[3] = (short)f2bf(a.w * scale);
            s[4] = (short)f2bf(c.x * scale); s[5] = (short)f2bf(c.y * scale);
            s[6] = (short)f2bf(c.z * scale); s[7] = (short)f2bf(c.w * scale);
            af[m][kw] = s;
        }
    }
    __syncthreads();
    const f32x4 zf = {0.f, 0.f, 0.f, 0.f};
    f32x4 acc[3][4];
    #pragma unroll
    for (int m = 0; m < 3; ++m)
        #pragma unroll
        for (int tt = 0; tt < 4; ++tt) acc[m][tt] = zf;
    #pragma unroll
    for (int tt = 0; tt < 4; ++tt)
        #pragma unroll
        for (int kw = 0; kw < 8; ++kw) {
            short8 bf = *(const short8*)(xl +
                swzX((u32)((16 * tt + q15) * 512 + kw * 64 + 16 * g)));
            acc[0][tt] = __builtin_amdgcn_mfma_f32_16x16x32_bf16(af[0][kw], bf, acc[0][tt], 0, 0, 0);
            acc[1][tt] = __builtin_amdgcn_mfma_f32_16x16x32_bf16(af[1][kw], bf, acc[1][tt], 0, 0, 0);
            acc[2][tt] = __builtin_amdgcn_mfma_f32_16x16x32_bf16(af[2][kw], bf, acc[2][tt], 0, 0, 0);
        }
    u16* qo = QT + (size_t)b * (DK * TT);
    u16* ko = KT + (size_t)b * (DK * TT);
    u16* vo = VT + (size_t)b * (DK * TT);
    #pragma unroll
    for (int tt = 0; tt < 4; ++tt) {
        int t = t0 + 16 * tt + q15;
        #pragma unroll
        for (int r = 0; r < 4; ++r) {
            int d = 16 * w + 4 * g + r;
            qo[(size_t)d * TT + t] = f2bf(acc[0][tt][r]);
            ko[(size_t)d * TT + t] = f2bf(acc[1][tt][r]);
            vo[(size_t)d * TT + t] = f2bf(acc[2][tt][r]);
        }
    }
}

// -------------------- K3: flash attention, KV-split x4, 2 tiles per barrier ----------
// Double k/v LDS buffers: stage BOTH tiles -> 1 barrier -> compute both -> 1
// barrier. 8 barriers/block (was 16). Max-free softmax (exp2, scale folded in
// Q). Emits bf16 raw O partials + fp32 l.
__global__ __launch_bounds__(256) void flash_kernel(
    const u16* __restrict__ QT, const u16* __restrict__ KT,
    const u16* __restrict__ VT, u16* __restrict__ XP, float* __restrict__ ML)
{
    __shared__ u16 k_lds[2][4096];   // [buf][64 kv][64 d], swzB (transpose-packed)
    __shared__ u16 v_lds[2][4096];   // [buf][64 d][64 kv], swzA (direct copy of V^T)
    __shared__ u16 p_lds[4][1024];   // per-wave [16 q][64 kv], swzA

    const int tid  = threadIdx.x;
    const int lane = tid & 63;
    const int w    = tid >> 6;
    const int g    = lane >> 4;
    const int q15  = lane & 15;

    const int bi   = blockIdx.x & 7;             // XCD-aligned: batch per XCD
    const int rest = blockIdx.x >> 3;
    const int qt   = rest & 31;
    const int quar = rest >> 5;                  // KV quarter 0..3
    const int q0 = qt * 64 + w * 16;
    const size_t boff = (size_t)bi * (DK * TT);

    const u16* Qb = QT + boff;
    const u16* Kb = KT + boff;
    const u16* Vb = VT + boff;

    short8 qf0, qf1;
    #pragma unroll
    for (int e = 0; e < 8; ++e) {
        qf0[e] = (short)Qb[(size_t)(8 * g + e) * TT + q0 + q15];
        qf1[e] = (short)Qb[(size_t)(8 * g + e + 32) * TT + q0 + q15];
    }

    float lrun = 0.f;                            // per-lane partial sum
    const f32x4 zf = {0.f, 0.f, 0.f, 0.f};
    f32x4 oacc[4];
    #pragma unroll
    for (int i = 0; i < 4; ++i) oacc[i] = zf;

    const int s2 = tid >> 3, c8 = tid & 7;
    const int kv0 = quar * 512;
    char* pl = (char*)p_lds[w];

    // staging registers for a PAIR of tiles
    uint4 ka[2], kb2[2], va[2], vb2[2];
    #pragma unroll
    for (int h = 0; h < 2; ++h) {
        const int kb = kv0 + h * 64;
        ka[h]  = *(const uint4*)(Kb + (size_t)(2 * s2) * TT + kb + c8 * 8);
        kb2[h] = *(const uint4*)(Kb + (size_t)(2 * s2 + 1) * TT + kb + c8 * 8);
        va[h]  = *(const uint4*)(Vb + (size_t)s2 * TT + kb + c8 * 8);
        vb2[h] = *(const uint4*)(Vb + (size_t)(s2 + 32) * TT + kb + c8 * 8);
    }

    // one tile's compute: QK^T -> exp2 -> P pack -> PV accumulate
    auto tile_compute = [&](char* kl, char* vl) {
        f32x4 sa[4];
        __builtin_amdgcn_s_setprio(1);
        #pragma unroll
        for (int f = 0; f < 4; ++f) {
            short8 k0 = *(const short8*)(kl + swzB((u32)((16 * f + q15) * 128 + 16 * g)));
            short8 k1 = *(const short8*)(kl + swzB((u32)((16 * f + q15) * 128 + 64 + 16 * g)));
            f32x4 t = __builtin_amdgcn_mfma_f32_16x16x32_bf16(k0, qf0, zf, 0, 0, 0);
            sa[f]   = __builtin_amdgcn_mfma_f32_16x16x32_bf16(k1, qf1, t, 0, 0, 0);
        }
        __builtin_amdgcn_s_setprio(0);
        float p[4][4];
        #pragma unroll
        for (int f = 0; f < 4; ++f)
            #pragma unroll
            for (int r = 0; r < 4; ++r) {
                p[f][r] = exp2f(sa[f][r]);       // scale folded in Q at qkv time
                lrun += p[f][r];
            }
        #pragma unroll
        for (int f = 0; f < 4; ++f) {
            uint2 pw;
            pw.x = cvtpk(p[f][0], p[f][1]);
            pw.y = cvtpk(p[f][2], p[f][3]);
            *(uint2*)(pl + swzA((u32)(q15 * 128 + f * 32 + g * 8))) = pw;
        }
        asm volatile("s_waitcnt lgkmcnt(0)" ::: "memory");
        __builtin_amdgcn_sched_barrier(0);        // rule #18: pin MFMA after wait
        short8 pf0 = *(const short8*)(pl + swzA((u32)(q15 * 128 + 16 * g)));
        short8 pf1 = *(const short8*)(pl + swzA((u32)(q15 * 128 + 64 + 16 * g)));
        __builtin_amdgcn_s_setprio(1);
        #pragma unroll
        for (int dt = 0; dt < 4; ++dt) {
            short8 v0 = *(const short8*)(vl + swzA((u32)((16 * dt + q15) * 128 + 16 * g)));
            short8 v1 = *(const short8*)(vl + swzA((u32)((16 * dt + q15) * 128 + 64 + 16 * g)));
            oacc[dt] = __builtin_amdgcn_mfma_f32_16x16x32_bf16(v0, pf0, oacc[dt], 0, 0, 0);
            oacc[dt] = __builtin_amdgcn_mfma_f32_16x16x32_bf16(v1, pf1, oacc[dt], 0, 0, 0);
        }
        __builtin_amdgcn_s_setprio(0);
    };

    for (int pr = 0; pr < 4; ++pr) {
        // ---- stage BOTH tiles of the pair ----
        #pragma unroll
        for (int h = 0; h < 2; ++h) {
            char* kl = (char*)k_lds[h];
            char* vl = (char*)v_lds[h];
            u32 a[4] = {ka[h].x, ka[h].y, ka[h].z, ka[h].w};
            u32 b[4] = {kb2[h].x, kb2[h].y, kb2[h].z, kb2[h].w};
            #pragma unroll
            for (int hh = 0; hh < 4; ++hh) {
                u32 w0 = (a[hh] & 0xFFFFu) | (b[hh] << 16);
                u32 w1 = (a[hh] >> 16) | (b[hh] & 0xFFFF0000u);
                int kvr = c8 * 8 + hh * 2;
                *(u32*)(kl + swzB((u32)(kvr * 128 + s2 * 4)))       = w0;
                *(u32*)(kl + swzB((u32)((kvr + 1) * 128 + s2 * 4))) = w1;
            }
            *(uint4*)(vl + swzA((u32)(tid * 16)))        = va[h];
            *(uint4*)(vl + swzA((u32)(tid * 16 + 4096))) = vb2[h];
        }
        __syncthreads();
        // ---- issue next pair's loads (hide under 2 tiles of compute) ----
        if (pr + 1 < 4) {
            #pragma unroll
            for (int h = 0; h < 2; ++h) {
                const int kb = kv0 + (pr + 1) * 128 + h * 64;
                ka[h]  = *(const uint4*)(Kb + (size_t)(2 * s2) * TT + kb + c8 * 8);
                kb2[h] = *(const uint4*)(Kb + (size_t)(2 * s2 + 1) * TT + kb + c8 * 8);
                va[h]  = *(const uint4*)(Vb + (size_t)s2 * TT + kb + c8 * 8);
                vb2[h] = *(const uint4*)(Vb + (size_t)(s2 + 32) * TT + kb + c8 * 8);
            }
        }
        tile_compute((char*)k_lds[0], (char*)v_lds[0]);
        tile_compute((char*)k_lds[1], (char*)v_lds[1]);
        __syncthreads();
    }
    // ---- epilogue: bf16 raw partial O + fp32 l (single cross-lane reduce) ----
    lrun += __shfl_xor(lrun, 16);
    lrun += __shfl_xor(lrun, 32);
    const size_t row = (size_t)bi * TT + q0 + q15;
    u16* xo = XP + (size_t)quar * XPH + row * DK;
    #pragma unroll
    for (int dt = 0; dt < 4; ++dt) {
        uint2 o;
        o.x = cvtpk(oacc[dt][0], oacc[dt][1]);
        o.y = cvtpk(oacc[dt][2], oacc[dt][3]);
        *(uint2*)(xo + 16 * dt + 4 * g) = o;
    }
    if (g == 0)
        ML[(size_t)quar * MLQ + row] = lrun;
}

// -------------------- K4: proj GEMM + 4-way sum-combine: ADb(B,C,T) bf16 -------------
__global__ __launch_bounds__(256) void proj_kernel(
    const u16* __restrict__ XP, const float* __restrict__ ML,
    const float* __restrict__ Wp, const float* __restrict__ gate,
    u16* __restrict__ ADb)
{
    __shared__ u16 xa_lds[64 * 64];      // [t][d], swzA
    const int tid = threadIdx.x;
    const int lane = tid & 63, w = tid >> 6, g = lane >> 4, q15 = lane & 15;
    const int b = blockIdx.x >> 5, t0 = (blockIdx.x & 31) * 64;
    char* xl = (char*)xa_lds;
    // stage XA tile (64t x 64d): max-free combine = plain sum of bf16 partials
    {
        const size_t q = (size_t)b * TT + t0 + (tid >> 2);
        const float inv = 1.0f / (ML[q] + ML[MLQ + q] + ML[2 * MLQ + q] + ML[3 * MLQ + q]);
        const int dq = (tid & 3) * 16;
        float c[16];
        #pragma unroll
        for (int e = 0; e < 16; ++e) c[e] = 0.f;
        #pragma unroll
        for (int h = 0; h < 4; ++h) {
            const u16* pr = XP + (size_t)h * XPH + q * DK + dq;
            uint4 u0 = *(const uint4*)(pr);
            uint4 u1 = *(const uint4*)(pr + 8);
            u32 uv[8] = {u0.x, u0.y, u0.z, u0.w, u1.x, u1.y, u1.z, u1.w};
            #pragma unroll
            for (int k = 0; k < 8; ++k) {
                c[2 * k]     += __builtin_bit_cast(float, uv[k] << 16);
                c[2 * k + 1] += __builtin_bit_cast(float, uv[k] & 0xFFFF0000u);
            }
        }
        #pragma unroll
        for (int e = 0; e < 16; ++e) c[e] *= inv;
        u32 base = (u32)((tid >> 2) * 128 + (tid & 3) * 32);
        uint4 w0 = {pk2(c[0], c[1]), pk2(c[2], c[3]), pk2(c[4], c[5]), pk2(c[6], c[7])};
        uint4 w1 = {pk2(c[8], c[9]), pk2(c[10], c[11]), pk2(c[12], c[13]), pk2(c[14], c[15])};
        *(uint4*)(xl + swzA(base))      = w0;
        *(uint4*)(xl + swzA(base + 16)) = w1;
    }
    short8 af[4][2];
    #pragma unroll
    for (int ci = 0; ci < 4; ++ci) {
        const float* wr = Wp + (size_t)(16 * (4 * w + ci) + q15) * DK + 8 * g;
        #pragma unroll
        for (int kw = 0; kw < 2; ++kw) {
            float4 a = *(const float4*)(wr + kw * 32);
            float4 c = *(const float4*)(wr + kw * 32 + 4);
            short8 s;
            s[0] = (short)f2bf(a.x); s[1] = (short)f2bf(a.y);
            s[2] = (short)f2bf(a.z); s[3] = (short)f2bf(a.w);
            s[4] = (short)f2bf(c.x); s[5] = (short)f2bf(c.y);
            s[6] = (short)f2bf(c.z); s[7] = (short)f2bf(c.w);
            af[ci][kw] = s;
        }
    }
    __syncthreads();
    const f32x4 zf = {0.f, 0.f, 0.f, 0.f};
    f32x4 acc[4][4];
    #pragma unroll
    for (int ci = 0; ci < 4; ++ci)
        #pragma unroll
        for (int tt = 0; tt < 4; ++tt) acc[ci][tt] = zf;
    #pragma unroll
    for (int tt = 0; tt < 4; ++tt)
        #pragma unroll
        for (int kw = 0; kw < 2; ++kw) {
            short8 bf = *(const short8*)(xl +
                swzA((u32)((16 * tt + q15) * 128 + kw * 64 + 16 * g)));
            #pragma unroll
            for (int ci = 0; ci < 4; ++ci)
                acc[ci][tt] = __builtin_amdgcn_mfma_f32_16x16x32_bf16(af[ci][kw], bf, acc[ci][tt], 0, 0, 0);
        }
    const float sg = 1.0f / (1.0f + __expf(-gate[0]));
    u16* ad = ADb + (size_t)b * (CC * TT);
    #pragma unroll
    for (int ci = 0; ci < 4; ++ci)
        #pragma unroll
        for (int tt = 0; tt < 4; ++tt) {
            int t = t0 + 16 * tt + q15;
            #pragma unroll
            for (int r = 0; r < 4; ++r) {
                int c = 16 * (4 * w + ci) + 4 * g + r;
                ad[(size_t)c * TT + t] = f2bf(sg * acc[ci][tt][r]);
            }
        }
}

// -------------------- K5: residual broadcast-add: out = x + ADb[b,c,t] over V --------
// REVERSED block order: pool streamed x ascending, so x's tail is L3-resident;
// consuming tail-first converts part of the re-read into L3 hits.
__global__ void final_kernel(const float* __restrict__ x, const u16* __restrict__ ADb,
                             float* __restrict__ out) {
    __shared__ float ad_lds[TT];
    const int tid = threadIdx.x;
    const int blk = (BB * CC - 1) - blockIdx.x;      // reverse order
    {
        uint4 v = ((const uint4*)(ADb + (size_t)blk * TT))[tid];
        u32 ww[4] = {v.x, v.y, v.z, v.w};
        #pragma unroll
        for (int k = 0; k < 4; ++k) {
            float lo = __builtin_bit_cast(float, ww[k] << 16);
            float hi = __builtin_bit_cast(float, ww[k] & 0xFFFF0000u);
            float2 pr = {lo, hi};
            *(float2*)&ad_lds[8 * tid + 2 * k] = pr;
        }
    }
    __syncthreads();
    const size_t base = (size_t)blk * (TT * VV);
    #pragma unroll 2
    for (int it = 0; it < (TT * VV) / (256 * 4); ++it) {
        int e = (it * 256 + tid) * 4;
        float4 xv = *(const float4*)&x[base + e];
        float4 ov;
        ov.x = xv.x + ad_lds[(e) / 25];
        ov.y = xv.y + ad_lds[(e + 1) / 25];
        ov.z = xv.z + ad_lds[(e + 2) / 25];
        ov.w = xv.w + ad_lds[(e + 3) / 25];
        *(float4*)&out[base + e] = ov;
    }
}

extern "C" void kernel_launch(void* const* d_in, const int* in_sizes, int n_in,
                              void* d_out, int out_size, void* d_ws, size_t ws_size,
                              hipStream_t stream) {
    const float* x    = (const float*)d_in[0];
    const float* Wq   = (const float*)d_in[1];
    const float* Wk   = (const float*)d_in[2];
    const float* Wv   = (const float*)d_in[3];
    const float* Wp   = (const float*)d_in[4];
    const float* gate = (const float*)d_in[5];
    float* out = (float*)d_out;
    float* ws = (float*)d_ws;

    // ws layout (float offsets):
    //   p0b  @ 0         (1,048,576 floats = B*C*T u16)
    //   ADb  @ 1048576   (2,097,152 floats = B*C*T u16? no: B*C*T u16 = 2,097,152 fl/2)
    //         B*C*T = 4,194,304 u16 = 2,097,152 floats
    //   XPb  @ 3145728   (4 x 1,048,576 u16 = 2,097,152 floats)
    //   ML   @ 5242880   (65,536 floats)
    //   QT   @ 5308416   (524,288 floats = B*DK*T u16)
    //   KT   @ 5832704   (524,288)
    //   VT   @ 6356992   (524,288)  ends 6,881,280 floats = 26.25 MB
    u16*   p0b = (u16*)(ws);
    u16*   ADb = (u16*)(ws + 1048576);
    u16*   XPb = (u16*)(ws + 3145728);
    float* MLb = ws + 5242880;
    u16*   QT  = (u16*)(ws + 5308416);
    u16*   KT  = (u16*)(ws + 5832704);
    u16*   VT  = (u16*)(ws + 6356992);

    pool_kernel<<<2048, 128, 0, stream>>>(x, p0b);                       // x -> (B,C,T) bf16
    qkv_gemm<<<256, 256, 0, stream>>>(p0b, Wq, Wk, Wv, QT, KT, VT);      // -> (B,64,T) bf16
    flash_kernel<<<1024, 256, 0, stream>>>(QT, KT, VT, XPb, MLb);        // -> bf16 partials x4
    proj_kernel<<<256, 256, 0, stream>>>(XPb, MLb, Wp, gate, ADb);       // sum-combine + GEMM
    final_kernel<<<2048, 256, 0, stream>>>(x, ADb, out);
}

// Round 8
// 331.617 us; speedup vs baseline: 1.0912x; 1.0912x over previous
//
#include <hip/hip_runtime.h>
#include <math.h>

// Problem constants (B, C, T, V, d_k) = (8, 256, 2048, 25, 64)
#define BB 8
#define CC 256
#define TT 2048
#define VV 25
#define DK 64
#define XPH 1048576   // B*T*DK u16 elements per KV-split quarter
#define MLQ 16384     // B*T floats (l only; max-free softmax) per quarter

typedef unsigned short u16;
typedef unsigned int u32;
typedef float f32x4 __attribute__((ext_vector_type(4)));
typedef short short8 __attribute__((ext_vector_type(8)));

__device__ __forceinline__ u16 f2bf(float x) {
    u32 u = __builtin_bit_cast(u32, x);
    u32 r = (u + 0x7FFFu + ((u >> 16) & 1u)) >> 16;   // RNE
    return (u16)r;
}
__device__ __forceinline__ u32 pk2(float a, float b) {
    return (u32)f2bf(a) | ((u32)f2bf(b) << 16);
}
// HW packed cvt (T12, m214v22): D.lo = bf16(S0), D.hi = bf16(S1), RNE
__device__ __forceinline__ u32 cvtpk(float a, float b) {
    u32 r;
    asm("v_cvt_pk_bf16_f32 %0, %1, %2" : "=v"(r) : "v"(a), "v"(b));
    return r;
}

// XOR swizzles (T2). Row-stride-128B tiles: swzA f(row)=row&7; swzB adds row>>3
// (for transpose-scatter writes). swzX: row-stride-512B tiles (row at bit 9).
__device__ __forceinline__ u32 swzA(u32 byte) {
    return byte ^ (((byte >> 7) & 7u) << 4);
}
__device__ __forceinline__ u32 swzB(u32 byte) {
    u32 row = byte >> 7;
    return byte ^ ((((row & 7u) ^ ((row >> 3) & 7u))) << 4);
}
__device__ __forceinline__ u32 swzX(u32 byte) {
    return byte ^ (((byte >> 9) & 7u) << 4);
}

// -------------------- K1: pool over V: x (B,C,T,V) -> p0 (B,C,T) bf16 ----------------
// Wave-local LDS staging: each wave owns a 12.8 KB region (128 rows x 25),
// no __syncthreads anywhere — ordering is in-wave lgkmcnt only. 2048 blocks
// x 4 waves x 4 chunks = 32768 chunks of 128 rows.
__global__ __launch_bounds__(256) void pool_kernel(const float* __restrict__ x,
                                                   u16* __restrict__ p0) {
    __shared__ float lds[4][128 * VV];
    const int lane = threadIdx.x & 63, w = threadIdx.x >> 6;
    float* buf = lds[w];
    const int ch0 = (blockIdx.x * 4 + w) * 4;
    #pragma unroll 1
    for (int it = 0; it < 4; ++it) {
        const long long ch = ch0 + it;
        const uint2* xu = (const uint2*)(x + ch * (128LL * VV));
        #pragma unroll
        for (int j = 0; j < VV; ++j)
            *(uint2*)&buf[2 * (lane + 64 * j)] = xu[lane + 64 * j];
        // lane reads back its 2 rows (50 consecutive floats at 50*lane);
        // compiler inserts the lgkmcnt wait (same-wave LDS RAW).
        float s0 = 0.f, s1 = 0.f;
        #pragma unroll
        for (int j = 0; j < VV; ++j) {
            s0 += buf[50 * lane + j];
            s1 += buf[50 * lane + VV + j];
        }
        *(u32*)&p0[ch * 128 + 2 * lane] = pk2(s0 * (1.0f / 25.0f),
                                              s1 * (1.0f / 25.0f));
    }
}

// -------------------- K2: fused QKV GEMM: Qt/Kt/Vt (B,64,T) = W @ p0(B,C,T) ----------
// 256 blocks = 8b x 32 t-chunks(64). p0 is bf16: stage = bit-merge only.
// Q pre-scaled by (1/8)*log2(e) so flash softmax uses bare exp2.
__global__ __launch_bounds__(256) void qkv_gemm(
    const u16* __restrict__ p0, const float* __restrict__ Wq,
    const float* __restrict__ Wk, const float* __restrict__ Wv,
    u16* __restrict__ QT, u16* __restrict__ KT, u16* __restrict__ VT)
{
    __shared__ u16 xlds[64 * 256];       // [t][c], swzX
    const int tid = threadIdx.x;
    const int lane = tid & 63, w = tid >> 6, g = lane >> 4, q15 = lane & 15;
    const int b = blockIdx.x >> 5, t0 = (blockIdx.x & 31) * 64;
    const u16* p0b = p0 + (size_t)b * (CC * TT);

    // stage x_t^T tile (bf16 in, [t][c] packed pairs out)
    const int c0 = (tid & 127) * 2, th = tid >> 7;
    char* xl = (char*)xlds;
    {
        const u16* r0p = p0b + (size_t)c0 * TT + t0 + th * 32;
        const u16* r1p = r0p + TT;
        #pragma unroll
        for (int j = 0; j < 4; ++j) {
            uint4 a = ((const uint4*)r0p)[j];    // 8 t's of row c0
            uint4 bq = ((const uint4*)r1p)[j];   // 8 t's of row c0+1
            u32 av[4] = {a.x, a.y, a.z, a.w};
            u32 bv[4] = {bq.x, bq.y, bq.z, bq.w};
            #pragma unroll
            for (int e = 0; e < 4; ++e) {
                int tb = th * 32 + j * 8 + e * 2;
                u32 w0 = (av[e] & 0xFFFFu) | (bv[e] << 16);
                u32 w1 = (av[e] >> 16) | (bv[e] & 0xFFFF0000u);
                *(u32*)(xl + swzX((u32)(tb * 512 + c0 * 2)))       = w0;
                *(u32*)(xl + swzX((u32)((tb + 1) * 512 + c0 * 2))) = w1;
            }
        }
    }
    short8 af[3][8];
    const float* Wmats[3] = {Wq, Wk, Wv};
    #pragma unroll
    for (int m = 0; m < 3; ++m) {
        const float* wr = Wmats[m] + (16 * w + q15) * 256 + 8 * g;
        const float scale = (m == 0) ? 0.125f * 1.44269504089f : 1.0f;  // fold log2(e)
        #pragma unroll
        for (int kw = 0; kw < 8; ++kw) {
            float4 a = *(const float4*)(wr + kw * 32);
            float4 c = *(const float4*)(wr + kw * 32 + 4);
            short8 s;
            s[0] = (short)f2bf(a.x * scale); s[1] = (short)f2bf(a.y * scale);
            s[2] = (short)f2bf(a.z * scale); s[3] = (short)f2bf(a.w * scale);
            s[4] = (short)f2bf(c.x * scale); s[5] = (short)f2bf(c.y * scale);
            s[6] = (short)f2bf(c.z * scale); s[7] = (short)f2bf(c.w * scale);
            af[m][kw] = s;
        }
    }
    __syncthreads();
    const f32x4 zf = {0.f, 0.f, 0.f, 0.f};
    f32x4 acc[3][4];
    #pragma unroll
    for (int m = 0; m < 3; ++m)
        #pragma unroll
        for (int tt = 0; tt < 4; ++tt) acc[m][tt] = zf;
    #pragma unroll
    for (int tt = 0; tt < 4; ++tt)
        #pragma unroll
        for (int kw = 0; kw < 8; ++kw) {
            short8 bf = *(const short8*)(xl +
                swzX((u32)((16 * tt + q15) * 512 + kw * 64 + 16 * g)));
            acc[0][tt] = __builtin_amdgcn_mfma_f32_16x16x32_bf16(af[0][kw], bf, acc[0][tt], 0, 0, 0);
            acc[1][tt] = __builtin_amdgcn_mfma_f32_16x16x32_bf16(af[1][kw], bf, acc[1][tt], 0, 0, 0);
            acc[2][tt] = __builtin_amdgcn_mfma_f32_16x16x32_bf16(af[2][kw], bf, acc[2][tt], 0, 0, 0);
        }
    u16* qo = QT + (size_t)b * (DK * TT);
    u16* ko = KT + (size_t)b * (DK * TT);
    u16* vo = VT + (size_t)b * (DK * TT);
    #pragma unroll
    for (int tt = 0; tt < 4; ++tt) {
        int t = t0 + 16 * tt + q15;
        #pragma unroll
        for (int r = 0; r < 4; ++r) {
            int d = 16 * w + 4 * g + r;
            qo[(size_t)d * TT + t] = f2bf(acc[0][tt][r]);
            ko[(size_t)d * TT + t] = f2bf(acc[1][tt][r]);
            vo[(size_t)d * TT + t] = f2bf(acc[2][tt][r]);
        }
    }
}

// -------------------- K3: flash attention, KV-split x4, single-buffer (6 blk/CU) -----
// R6 structure (24 KB LDS) + exp2 softmax (scale folded in Q) + bf16 partials.
__global__ __launch_bounds__(256) void flash_kernel(
    const u16* __restrict__ QT, const u16* __restrict__ KT,
    const u16* __restrict__ VT, u16* __restrict__ XP, float* __restrict__ ML)
{
    __shared__ u16 k_lds[4096];      // [64 kv][64 d], swzB (transpose-packed)
    __shared__ u16 v_lds[4096];      // [64 d][64 kv], swzA (direct copy of V^T)
    __shared__ u16 p_lds[4][1024];   // per-wave [16 q][64 kv], swzA

    const int tid  = threadIdx.x;
    const int lane = tid & 63;
    const int w    = tid >> 6;
    const int g    = lane >> 4;
    const int q15  = lane & 15;

    const int bi   = blockIdx.x & 7;             // XCD-aligned: batch per XCD
    const int rest = blockIdx.x >> 3;
    const int qt   = rest & 31;
    const int quar = rest >> 5;                  // KV quarter 0..3
    const int q0 = qt * 64 + w * 16;
    const size_t boff = (size_t)bi * (DK * TT);

    const u16* Qb = QT + boff;
    const u16* Kb = KT + boff;
    const u16* Vb = VT + boff;

    short8 qf0, qf1;
    #pragma unroll
    for (int e = 0; e < 8; ++e) {
        qf0[e] = (short)Qb[(size_t)(8 * g + e) * TT + q0 + q15];
        qf1[e] = (short)Qb[(size_t)(8 * g + e + 32) * TT + q0 + q15];
    }

    float lrun = 0.f;                            // per-lane partial sum
    const f32x4 zf = {0.f, 0.f, 0.f, 0.f};
    f32x4 oacc[4];
    #pragma unroll
    for (int i = 0; i < 4; ++i) oacc[i] = zf;

    const int s2 = tid >> 3, c8 = tid & 7;
    const int kv0 = quar * 512;
    char* kl = (char*)k_lds;
    char* vl = (char*)v_lds;
    char* pl = (char*)p_lds[w];

    uint4 ka  = *(const uint4*)(Kb + (size_t)(2 * s2) * TT + kv0 + c8 * 8);
    uint4 kb2 = *(const uint4*)(Kb + (size_t)(2 * s2 + 1) * TT + kv0 + c8 * 8);
    uint4 va  = *(const uint4*)(Vb + (size_t)s2 * TT + kv0 + c8 * 8);
    uint4 vb2 = *(const uint4*)(Vb + (size_t)(s2 + 32) * TT + kv0 + c8 * 8);

    for (int it = 0; it < 8; ++it) {
        if (it) __syncthreads();                 // prev tile fully consumed
        // ---- K: transpose-pack regs -> k_lds[kv][d] (swzB) ----
        {
            u32 a[4] = {ka.x, ka.y, ka.z, ka.w};
            u32 b[4] = {kb2.x, kb2.y, kb2.z, kb2.w};
            #pragma unroll
            for (int h = 0; h < 4; ++h) {
                u32 w0 = (a[h] & 0xFFFFu) | (b[h] << 16);
                u32 w1 = (a[h] >> 16) | (b[h] & 0xFFFF0000u);
                int kvr = c8 * 8 + h * 2;
                *(u32*)(kl + swzB((u32)(kvr * 128 + s2 * 4)))       = w0;
                *(u32*)(kl + swzB((u32)((kvr + 1) * 128 + s2 * 4))) = w1;
            }
        }
        // ---- V: direct copy -> v_lds[d][kv] (swzA) ----
        *(uint4*)(vl + swzA((u32)(tid * 16)))        = va;
        *(uint4*)(vl + swzA((u32)(tid * 16 + 4096))) = vb2;
        __syncthreads();
        // ---- issue next tile's global loads (hide under compute) ----
        if (it + 1 < 8) {
            const int kb = kv0 + (it + 1) * 64;
            ka  = *(const uint4*)(Kb + (size_t)(2 * s2) * TT + kb + c8 * 8);
            kb2 = *(const uint4*)(Kb + (size_t)(2 * s2 + 1) * TT + kb + c8 * 8);
            va  = *(const uint4*)(Vb + (size_t)s2 * TT + kb + c8 * 8);
            vb2 = *(const uint4*)(Vb + (size_t)(s2 + 32) * TT + kb + c8 * 8);
        }
        // ---- QK^T (swapped): S^T[kv][q] = K.Q^T ----
        f32x4 sa[4];
        __builtin_amdgcn_s_setprio(1);
        #pragma unroll
        for (int f = 0; f < 4; ++f) {
            short8 k0 = *(const short8*)(kl + swzB((u32)((16 * f + q15) * 128 + 16 * g)));
            short8 k1 = *(const short8*)(kl + swzB((u32)((16 * f + q15) * 128 + 64 + 16 * g)));
            f32x4 t = __builtin_amdgcn_mfma_f32_16x16x32_bf16(k0, qf0, zf, 0, 0, 0);
            sa[f]   = __builtin_amdgcn_mfma_f32_16x16x32_bf16(k1, qf1, t, 0, 0, 0);
        }
        __builtin_amdgcn_s_setprio(0);
        // ---- max-free softmax: p = exp2(s), lane-local l accumulation ----
        float p[4][4];
        #pragma unroll
        for (int f = 0; f < 4; ++f)
            #pragma unroll
            for (int r = 0; r < 4; ++r) {
                p[f][r] = exp2f(sa[f][r]);       // scale folded in Q at qkv time
                lrun += p[f][r];
            }
        // ---- P -> bf16 (HW cvt_pk) -> per-wave LDS [q][kv] ----
        #pragma unroll
        for (int f = 0; f < 4; ++f) {
            uint2 pw;
            pw.x = cvtpk(p[f][0], p[f][1]);
            pw.y = cvtpk(p[f][2], p[f][3]);
            *(uint2*)(pl + swzA((u32)(q15 * 128 + f * 32 + g * 8))) = pw;
        }
        asm volatile("s_waitcnt lgkmcnt(0)" ::: "memory");
        __builtin_amdgcn_sched_barrier(0);        // rule #18: pin MFMA after wait
        // ---- PV: O^T[d][q] += V^T . P^T ----
        short8 pf0 = *(const short8*)(pl + swzA((u32)(q15 * 128 + 16 * g)));
        short8 pf1 = *(const short8*)(pl + swzA((u32)(q15 * 128 + 64 + 16 * g)));
        __builtin_amdgcn_s_setprio(1);
        #pragma unroll
        for (int dt = 0; dt < 4; ++dt) {
            short8 v0 = *(const short8*)(vl + swzA((u32)((16 * dt + q15) * 128 + 16 * g)));
            short8 v1 = *(const short8*)(vl + swzA((u32)((16 * dt + q15) * 128 + 64 + 16 * g)));
            oacc[dt] = __builtin_amdgcn_mfma_f32_16x16x32_bf16(v0, pf0, oacc[dt], 0, 0, 0);
            oacc[dt] = __builtin_amdgcn_mfma_f32_16x16x32_bf16(v1, pf1, oacc[dt], 0, 0, 0);
        }
        __builtin_amdgcn_s_setprio(0);
    }
    // ---- epilogue: bf16 raw partial O + fp32 l (single cross-lane reduce) ----
    lrun += __shfl_xor(lrun, 16);
    lrun += __shfl_xor(lrun, 32);
    const size_t row = (size_t)bi * TT + q0 + q15;
    u16* xo = XP + (size_t)quar * XPH + row * DK;
    #pragma unroll
    for (int dt = 0; dt < 4; ++dt) {
        uint2 o;
        o.x = cvtpk(oacc[dt][0], oacc[dt][1]);
        o.y = cvtpk(oacc[dt][2], oacc[dt][3]);
        *(uint2*)(xo + 16 * dt + 4 * g) = o;
    }
    if (g == 0)
        ML[(size_t)quar * MLQ + row] = lrun;
}

// -------------------- K4: proj GEMM + 4-way sum-combine: ADb(B,C,T) bf16 -------------
__global__ __launch_bounds__(256) void proj_kernel(
    const u16* __restrict__ XP, const float* __restrict__ ML,
    const float* __restrict__ Wp, const float* __restrict__ gate,
    u16* __restrict__ ADb)
{
    __shared__ u16 xa_lds[64 * 64];      // [t][d], swzA
    const int tid = threadIdx.x;
    const int lane = tid & 63, w = tid >> 6, g = lane >> 4, q15 = lane & 15;
    const int b = blockIdx.x >> 5, t0 = (blockIdx.x & 31) * 64;
    char* xl = (char*)xa_lds;
    // stage XA tile (64t x 64d): max-free combine = plain sum of bf16 partials
    {
        const size_t q = (size_t)b * TT + t0 + (tid >> 2);
        const float inv = 1.0f / (ML[q] + ML[MLQ + q] + ML[2 * MLQ + q] + ML[3 * MLQ + q]);
        const int dq = (tid & 3) * 16;
        float c[16];
        #pragma unroll
        for (int e = 0; e < 16; ++e) c[e] = 0.f;
        #pragma unroll
        for (int h = 0; h < 4; ++h) {
            const u16* pr = XP + (size_t)h * XPH + q * DK + dq;
            uint4 u0 = *(const uint4*)(pr);
            uint4 u1 = *(const uint4*)(pr + 8);
            u32 uv[8] = {u0.x, u0.y, u0.z, u0.w, u1.x, u1.y, u1.z, u1.w};
            #pragma unroll
            for (int k = 0; k < 8; ++k) {
                c[2 * k]     += __builtin_bit_cast(float, uv[k] << 16);
                c[2 * k + 1] += __builtin_bit_cast(float, uv[k] & 0xFFFF0000u);
            }
        }
        #pragma unroll
        for (int e = 0; e < 16; ++e) c[e] *= inv;
        u32 base = (u32)((tid >> 2) * 128 + (tid & 3) * 32);
        uint4 w0 = {pk2(c[0], c[1]), pk2(c[2], c[3]), pk2(c[4], c[5]), pk2(c[6], c[7])};
        uint4 w1 = {pk2(c[8], c[9]), pk2(c[10], c[11]), pk2(c[12], c[13]), pk2(c[14], c[15])};
        *(uint4*)(xl + swzA(base))      = w0;
        *(uint4*)(xl + swzA(base + 16)) = w1;
    }
    short8 af[4][2];
    #pragma unroll
    for (int ci = 0; ci < 4; ++ci) {
        const float* wr = Wp + (size_t)(16 * (4 * w + ci) + q15) * DK + 8 * g;
        #pragma unroll
        for (int kw = 0; kw < 2; ++kw) {
            float4 a = *(const float4*)(wr + kw * 32);
            float4 c = *(const float4*)(wr + kw * 32 + 4);
            short8 s;
            s[0] = (short)f2bf(a.x); s[1] = (short)f2bf(a.y);
            s[2] = (short)f2bf(a.z); s[3] = (short)f2bf(a.w);
            s[4] = (short)f2bf(c.x); s[5] = (short)f2bf(c.y);
            s[6] = (short)f2bf(c.z); s[7] = (short)f2bf(c.w);
            af[ci][kw] = s;
        }
    }
    __syncthreads();
    const f32x4 zf = {0.f, 0.f, 0.f, 0.f};
    f32x4 acc[4][4];
    #pragma unroll
    for (int ci = 0; ci < 4; ++ci)
        #pragma unroll
        for (int tt = 0; tt < 4; ++tt) acc[ci][tt] = zf;
    #pragma unroll
    for (int tt = 0; tt < 4; ++tt)
        #pragma unroll
        for (int kw = 0; kw < 2; ++kw) {
            short8 bf = *(const short8*)(xl +
                swzA((u32)((16 * tt + q15) * 128 + kw * 64 + 16 * g)));
            #pragma unroll
            for (int ci = 0; ci < 4; ++ci)
                acc[ci][tt] = __builtin_amdgcn_mfma_f32_16x16x32_bf16(af[ci][kw], bf, acc[ci][tt], 0, 0, 0);
        }
    const float sg = 1.0f / (1.0f + __expf(-gate[0]));
    u16* ad = ADb + (size_t)b * (CC * TT);
    #pragma unroll
    for (int ci = 0; ci < 4; ++ci)
        #pragma unroll
        for (int tt = 0; tt < 4; ++tt) {
            int t = t0 + 16 * tt + q15;
            #pragma unroll
            for (int r = 0; r < 4; ++r) {
                int c = 16 * (4 * w + ci) + 4 * g + r;
                ad[(size_t)c * TT + t] = f2bf(sg * acc[ci][tt][r]);
            }
        }
}

// -------------------- K5: residual broadcast-add: out = x + ADb[b,c,t] over V --------
// REVERSED block order: pool streamed x ascending, so x's tail is L3-resident;
// consuming tail-first converts part of the re-read into L3 hits.
__global__ void final_kernel(const float* __restrict__ x, const u16* __restrict__ ADb,
                             float* __restrict__ out) {
    __shared__ float ad_lds[TT];
    const int tid = threadIdx.x;
    const int blk = (BB * CC - 1) - blockIdx.x;      // reverse order
    {
        uint4 v = ((const uint4*)(ADb + (size_t)blk * TT))[tid];
        u32 ww[4] = {v.x, v.y, v.z, v.w};
        #pragma unroll
        for (int k = 0; k < 4; ++k) {
            float lo = __builtin_bit_cast(float, ww[k] << 16);
            float hi = __builtin_bit_cast(float, ww[k] & 0xFFFF0000u);
            float2 pr = {lo, hi};
            *(float2*)&ad_lds[8 * tid + 2 * k] = pr;
        }
    }
    __syncthreads();
    const size_t base = (size_t)blk * (TT * VV);
    #pragma unroll 2
    for (int it = 0; it < (TT * VV) / (256 * 4); ++it) {
        int e = (it * 256 + tid) * 4;
        float4 xv = *(const float4*)&x[base + e];
        float4 ov;
        ov.x = xv.x + ad_lds[(e) / 25];
        ov.y = xv.y + ad_lds[(e + 1) / 25];
        ov.z = xv.z + ad_lds[(e + 2) / 25];
        ov.w = xv.w + ad_lds[(e + 3) / 25];
        *(float4*)&out[base + e] = ov;
    }
}

extern "C" void kernel_launch(void* const* d_in, const int* in_sizes, int n_in,
                              void* d_out, int out_size, void* d_ws, size_t ws_size,
                              hipStream_t stream) {
    const float* x    = (const float*)d_in[0];
    const float* Wq   = (const float*)d_in[1];
    const float* Wk   = (const float*)d_in[2];
    const float* Wv   = (const float*)d_in[3];
    const float* Wp   = (const float*)d_in[4];
    const float* gate = (const float*)d_in[5];
    float* out = (float*)d_out;
    float* ws = (float*)d_ws;

    // ws layout (float offsets):
    //   p0b  @ 0         (1,048,576 floats = B*C*T u16)
    //   ADb  @ 1048576   (2,097,152 floats = B*C*T u16)
    //   XPb  @ 3145728   (4 x 1,048,576 u16 = 2,097,152 floats)
    //   ML   @ 5242880   (65,536 floats)
    //   QT   @ 5308416   (524,288 floats = B*DK*T u16)
    //   KT   @ 5832704   (524,288)
    //   VT   @ 6356992   (524,288)  ends 6,881,280 floats = 26.25 MB
    u16*   p0b = (u16*)(ws);
    u16*   ADb = (u16*)(ws + 1048576);
    u16*   XPb = (u16*)(ws + 3145728);
    float* MLb = ws + 5242880;
    u16*   QT  = (u16*)(ws + 5308416);
    u16*   KT  = (u16*)(ws + 5832704);
    u16*   VT  = (u16*)(ws + 6356992);

    pool_kernel<<<2048, 256, 0, stream>>>(x, p0b);                       // x -> (B,C,T) bf16
    qkv_gemm<<<256, 256, 0, stream>>>(p0b, Wq, Wk, Wv, QT, KT, VT);      // -> (B,64,T) bf16
    flash_kernel<<<1024, 256, 0, stream>>>(QT, KT, VT, XPb, MLb);        // -> bf16 partials x4
    proj_kernel<<<256, 256, 0, stream>>>(XPb, MLb, Wp, gate, ADb);       // sum-combine + GEMM
    final_kernel<<<2048, 256, 0, stream>>>(x, ADb, out);
}

// Round 10
// 255.930 us; speedup vs baseline: 1.4139x; 1.2957x over previous
//
#include <hip/hip_runtime.h>
#include <math.h>

// Problem constants (B, C, T, V, d_k) = (8, 256, 2048, 25, 64)
#define BB 8
#define CC 256
#define TT 2048
#define VV 25
#define DK 64
#define XPH 1048576   // B*T*DK u16 elements per KV-split quarter
#define MLQ 16384     // B*T floats (l only; max-free softmax) per quarter

typedef unsigned short u16;
typedef unsigned int u32;
typedef float f32x4 __attribute__((ext_vector_type(4)));
typedef short short8 __attribute__((ext_vector_type(8)));

__device__ __forceinline__ u16 f2bf(float x) {
    u32 u = __builtin_bit_cast(u32, x);
    u32 r = (u + 0x7FFFu + ((u >> 16) & 1u)) >> 16;   // RNE
    return (u16)r;
}
__device__ __forceinline__ u32 pk2(float a, float b) {
    return (u32)f2bf(a) | ((u32)f2bf(b) << 16);
}
// HW packed cvt (T12, m214v22): D.lo = bf16(S0), D.hi = bf16(S1), RNE
__device__ __forceinline__ u32 cvtpk(float a, float b) {
    u32 r;
    asm("v_cvt_pk_bf16_f32 %0, %1, %2" : "=v"(r) : "v"(a), "v"(b));
    return r;
}

// XOR swizzles (T2). Row-stride-128B tiles: swzA f(row)=row&7; swzB adds row>>3
// (for transpose-scatter writes). swzX: row-stride-512B tiles (row at bit 9).
__device__ __forceinline__ u32 swzA(u32 byte) {
    return byte ^ (((byte >> 7) & 7u) << 4);
}
__device__ __forceinline__ u32 swzB(u32 byte) {
    u32 row = byte >> 7;
    return byte ^ ((((row & 7u) ^ ((row >> 3) & 7u))) << 4);
}
__device__ __forceinline__ u32 swzX(u32 byte) {
    return byte ^ (((byte >> 9) & 7u) << 4);
}

// -------------------- K1: pool over V: x (B,C,T,V) -> p0 (B,C,T) bf16 ----------------
// Wave-local LDS staging: each wave owns a 12.8 KB region (128 rows x 25),
// no __syncthreads anywhere — ordering is in-wave lgkmcnt only.
__global__ __launch_bounds__(256) void pool_kernel(const float* __restrict__ x,
                                                   u16* __restrict__ p0) {
    __shared__ float lds[4][128 * VV];
    const int lane = threadIdx.x & 63, w = threadIdx.x >> 6;
    float* buf = lds[w];
    const int ch0 = (blockIdx.x * 4 + w) * 4;
    #pragma unroll 1
    for (int it = 0; it < 4; ++it) {
        const long long ch = ch0 + it;
        const uint2* xu = (const uint2*)(x + ch * (128LL * VV));
        #pragma unroll
        for (int j = 0; j < VV; ++j)
            *(uint2*)&buf[2 * (lane + 64 * j)] = xu[lane + 64 * j];
        float s0 = 0.f, s1 = 0.f;
        #pragma unroll
        for (int j = 0; j < VV; ++j) {
            s0 += buf[50 * lane + j];
            s1 += buf[50 * lane + VV + j];
        }
        *(u32*)&p0[ch * 128 + 2 * lane] = pk2(s0 * (1.0f / 25.0f),
                                              s1 * (1.0f / 25.0f));
    }
}

// -------------------- K2: fused QKV GEMM: QR (B,T,64); Kt/Vt (B,64,T) ----------------
// 256 blocks = 8b x 32 t-chunks(64). p0 is bf16: stage = bit-merge only.
// Q pre-scaled by (1/8)*log2(e), written ROW-major so flash loads 2 x uint4.
__global__ __launch_bounds__(256) void qkv_gemm(
    const u16* __restrict__ p0, const float* __restrict__ Wq,
    const float* __restrict__ Wk, const float* __restrict__ Wv,
    u16* __restrict__ QR, u16* __restrict__ KT, u16* __restrict__ VT)
{
    __shared__ u16 xlds[64 * 256];       // [t][c], swzX
    const int tid = threadIdx.x;
    const int lane = tid & 63, w = tid >> 6, g = lane >> 4, q15 = lane & 15;
    const int b = blockIdx.x >> 5, t0 = (blockIdx.x & 31) * 64;
    const u16* p0b = p0 + (size_t)b * (CC * TT);

    // stage x_t^T tile (bf16 in, [t][c] packed pairs out)
    const int c0 = (tid & 127) * 2, th = tid >> 7;
    char* xl = (char*)xlds;
    {
        const u16* r0p = p0b + (size_t)c0 * TT + t0 + th * 32;
        const u16* r1p = r0p + TT;
        #pragma unroll
        for (int j = 0; j < 4; ++j) {
            uint4 a = ((const uint4*)r0p)[j];    // 8 t's of row c0
            uint4 bq = ((const uint4*)r1p)[j];   // 8 t's of row c0+1
            u32 av[4] = {a.x, a.y, a.z, a.w};
            u32 bv[4] = {bq.x, bq.y, bq.z, bq.w};
            #pragma unroll
            for (int e = 0; e < 4; ++e) {
                int tb = th * 32 + j * 8 + e * 2;
                u32 w0 = (av[e] & 0xFFFFu) | (bv[e] << 16);
                u32 w1 = (av[e] >> 16) | (bv[e] & 0xFFFF0000u);
                *(u32*)(xl + swzX((u32)(tb * 512 + c0 * 2)))       = w0;
                *(u32*)(xl + swzX((u32)((tb + 1) * 512 + c0 * 2))) = w1;
            }
        }
    }
    short8 af[3][8];
    const float* Wmats[3] = {Wq, Wk, Wv};
    #pragma unroll
    for (int m = 0; m < 3; ++m) {
        const float* wr = Wmats[m] + (16 * w + q15) * 256 + 8 * g;
        const float scale = (m == 0) ? 0.125f * 1.44269504089f : 1.0f;  // fold log2(e)
        #pragma unroll
        for (int kw = 0; kw < 8; ++kw) {
            float4 a = *(const float4*)(wr + kw * 32);
            float4 c = *(const float4*)(wr + kw * 32 + 4);
            short8 s;
            s[0] = (short)f2bf(a.x * scale); s[1] = (short)f2bf(a.y * scale);
            s[2] = (short)f2bf(a.z * scale); s[3] = (short)f2bf(a.w * scale);
            s[4] = (short)f2bf(c.x * scale); s[5] = (short)f2bf(c.y * scale);
            s[6] = (short)f2bf(c.z * scale); s[7] = (short)f2bf(c.w * scale);
            af[m][kw] = s;
        }
    }
    __syncthreads();
    const f32x4 zf = {0.f, 0.f, 0.f, 0.f};
    f32x4 acc[3][4];
    #pragma unroll
    for (int m = 0; m < 3; ++m)
        #pragma unroll
        for (int tt = 0; tt < 4; ++tt) acc[m][tt] = zf;
    #pragma unroll
    for (int tt = 0; tt < 4; ++tt)
        #pragma unroll
        for (int kw = 0; kw < 8; ++kw) {
            short8 bf = *(const short8*)(xl +
                swzX((u32)((16 * tt + q15) * 512 + kw * 64 + 16 * g)));
            acc[0][tt] = __builtin_amdgcn_mfma_f32_16x16x32_bf16(af[0][kw], bf, acc[0][tt], 0, 0, 0);
            acc[1][tt] = __builtin_amdgcn_mfma_f32_16x16x32_bf16(af[1][kw], bf, acc[1][tt], 0, 0, 0);
            acc[2][tt] = __builtin_amdgcn_mfma_f32_16x16x32_bf16(af[2][kw], bf, acc[2][tt], 0, 0, 0);
        }
    u16* qo = QR + (size_t)b * (TT * DK);
    u16* ko = KT + (size_t)b * (DK * TT);
    u16* vo = VT + (size_t)b * (DK * TT);
    #pragma unroll
    for (int tt = 0; tt < 4; ++tt) {
        int t = t0 + 16 * tt + q15;
        // Q row-major: 4 consecutive d at d0 = 16w+4g -> one uint2
        uint2 qw;
        qw.x = pk2(acc[0][tt][0], acc[0][tt][1]);
        qw.y = pk2(acc[0][tt][2], acc[0][tt][3]);
        *(uint2*)&qo[(size_t)t * DK + 16 * w + 4 * g] = qw;
        #pragma unroll
        for (int r = 0; r < 4; ++r) {
            int d = 16 * w + 4 * g + r;
            ko[(size_t)d * TT + t] = f2bf(acc[1][tt][r]);
            vo[(size_t)d * TT + t] = f2bf(acc[2][tt][r]);
        }
    }
}

// -------------------- K3: flash attention, KV-split x4, single-buffer (6 blk/CU) -----
// R8 structure (24 KB LDS) + exp2 softmax (scale folded in Q) + bf16 partials.
// Q fragment loads as 2 x 16B from row-major QR.
__global__ __launch_bounds__(256) void flash_kernel(
    const u16* __restrict__ QR, const u16* __restrict__ KT,
    const u16* __restrict__ VT, u16* __restrict__ XP, float* __restrict__ ML)
{
    __shared__ u16 k_lds[4096];      // [64 kv][64 d], swzB (transpose-packed)
    __shared__ u16 v_lds[4096];      // [64 d][64 kv], swzA (direct copy of V^T)
    __shared__ u16 p_lds[4][1024];   // per-wave [16 q][64 kv], swzA

    const int tid  = threadIdx.x;
    const int lane = tid & 63;
    const int w    = tid >> 6;
    const int g    = lane >> 4;
    const int q15  = lane & 15;

    const int bi   = blockIdx.x & 7;             // XCD-aligned: batch per XCD
    const int rest = blockIdx.x >> 3;
    const int qt   = rest & 31;
    const int quar = rest >> 5;                  // KV quarter 0..3
    const int q0 = qt * 64 + w * 16;
    const size_t boff = (size_t)bi * (DK * TT);

    const u16* Kb = KT + boff;
    const u16* Vb = VT + boff;

    // Q fragment: lane holds Q[q0+q15][8g+e (+32)] — two 16B loads (row-major QR)
    short8 qf0, qf1;
    {
        const u16* qr = QR + boff + (size_t)(q0 + q15) * DK + 8 * g;
        qf0 = *(const short8*)(qr);
        qf1 = *(const short8*)(qr + 32);
    }

    float lrun = 0.f;                            // per-lane partial sum
    const f32x4 zf = {0.f, 0.f, 0.f, 0.f};
    f32x4 oacc[4];
    #pragma unroll
    for (int i = 0; i < 4; ++i) oacc[i] = zf;

    const int s2 = tid >> 3, c8 = tid & 7;
    const int kv0 = quar * 512;
    char* kl = (char*)k_lds;
    char* vl = (char*)v_lds;
    char* pl = (char*)p_lds[w];

    uint4 ka  = *(const uint4*)(Kb + (size_t)(2 * s2) * TT + kv0 + c8 * 8);
    uint4 kb2 = *(const uint4*)(Kb + (size_t)(2 * s2 + 1) * TT + kv0 + c8 * 8);
    uint4 va  = *(const uint4*)(Vb + (size_t)s2 * TT + kv0 + c8 * 8);
    uint4 vb2 = *(const uint4*)(Vb + (size_t)(s2 + 32) * TT + kv0 + c8 * 8);

    for (int it = 0; it < 8; ++it) {
        if (it) __syncthreads();                 // prev tile fully consumed
        // ---- K: transpose-pack regs -> k_lds[kv][d] (swzB) ----
        {
            u32 a[4] = {ka.x, ka.y, ka.z, ka.w};
            u32 b[4] = {kb2.x, kb2.y, kb2.z, kb2.w};
            #pragma unroll
            for (int h = 0; h < 4; ++h) {
                u32 w0 = (a[h] & 0xFFFFu) | (b[h] << 16);
                u32 w1 = (a[h] >> 16) | (b[h] & 0xFFFF0000u);
                int kvr = c8 * 8 + h * 2;
                *(u32*)(kl + swzB((u32)(kvr * 128 + s2 * 4)))       = w0;
                *(u32*)(kl + swzB((u32)((kvr + 1) * 128 + s2 * 4))) = w1;
            }
        }
        // ---- V: direct copy -> v_lds[d][kv] (swzA) ----
        *(uint4*)(vl + swzA((u32)(tid * 16)))        = va;
        *(uint4*)(vl + swzA((u32)(tid * 16 + 4096))) = vb2;
        __syncthreads();
        // ---- issue next tile's global loads (hide under compute) ----
        if (it + 1 < 8) {
            const int kb = kv0 + (it + 1) * 64;
            ka  = *(const uint4*)(Kb + (size_t)(2 * s2) * TT + kb + c8 * 8);
            kb2 = *(const uint4*)(Kb + (size_t)(2 * s2 + 1) * TT + kb + c8 * 8);
            va  = *(const uint4*)(Vb + (size_t)s2 * TT + kb + c8 * 8);
            vb2 = *(const uint4*)(Vb + (size_t)(s2 + 32) * TT + kb + c8 * 8);
        }
        // ---- QK^T (swapped): S^T[kv][q] = K.Q^T ----
        f32x4 sa[4];
        __builtin_amdgcn_s_setprio(1);
        #pragma unroll
        for (int f = 0; f < 4; ++f) {
            short8 k0 = *(const short8*)(kl + swzB((u32)((16 * f + q15) * 128 + 16 * g)));
            short8 k1 = *(const short8*)(kl + swzB((u32)((16 * f + q15) * 128 + 64 + 16 * g)));
            f32x4 t = __builtin_amdgcn_mfma_f32_16x16x32_bf16(k0, qf0, zf, 0, 0, 0);
            sa[f]   = __builtin_amdgcn_mfma_f32_16x16x32_bf16(k1, qf1, t, 0, 0, 0);
        }
        __builtin_amdgcn_s_setprio(0);
        // ---- max-free softmax: p = exp2(s), lane-local l accumulation ----
        float p[4][4];
        #pragma unroll
        for (int f = 0; f < 4; ++f)
            #pragma unroll
            for (int r = 0; r < 4; ++r) {
                p[f][r] = exp2f(sa[f][r]);       // scale folded in Q at qkv time
                lrun += p[f][r];
            }
        // ---- P -> bf16 (HW cvt_pk) -> per-wave LDS [q][kv] ----
        #pragma unroll
        for (int f = 0; f < 4; ++f) {
            uint2 pw;
            pw.x = cvtpk(p[f][0], p[f][1]);
            pw.y = cvtpk(p[f][2], p[f][3]);
            *(uint2*)(pl + swzA((u32)(q15 * 128 + f * 32 + g * 8))) = pw;
        }
        asm volatile("s_waitcnt lgkmcnt(0)" ::: "memory");
        __builtin_amdgcn_sched_barrier(0);        // rule #18: pin MFMA after wait
        // ---- PV: O^T[d][q] += V^T . P^T ----
        short8 pf0 = *(const short8*)(pl + swzA((u32)(q15 * 128 + 16 * g)));
        short8 pf1 = *(const short8*)(pl + swzA((u32)(q15 * 128 + 64 + 16 * g)));
        __builtin_amdgcn_s_setprio(1);
        #pragma unroll
        for (int dt = 0; dt < 4; ++dt) {
            short8 v0 = *(const short8*)(vl + swzA((u32)((16 * dt + q15) * 128 + 16 * g)));
            short8 v1 = *(const short8*)(vl + swzA((u32)((16 * dt + q15) * 128 + 64 + 16 * g)));
            oacc[dt] = __builtin_amdgcn_mfma_f32_16x16x32_bf16(v0, pf0, oacc[dt], 0, 0, 0);
            oacc[dt] = __builtin_amdgcn_mfma_f32_16x16x32_bf16(v1, pf1, oacc[dt], 0, 0, 0);
        }
        __builtin_amdgcn_s_setprio(0);
    }
    // ---- epilogue: bf16 raw partial O + fp32 l (single cross-lane reduce) ----
    lrun += __shfl_xor(lrun, 16);
    lrun += __shfl_xor(lrun, 32);
    const size_t row = (size_t)bi * TT + q0 + q15;
    u16* xo = XP + (size_t)quar * XPH + row * DK;
    #pragma unroll
    for (int dt = 0; dt < 4; ++dt) {
        uint2 o;
        o.x = cvtpk(oacc[dt][0], oacc[dt][1]);
        o.y = cvtpk(oacc[dt][2], oacc[dt][3]);
        *(uint2*)(xo + 16 * dt + 4 * g) = o;
    }
    if (g == 0)
        ML[(size_t)quar * MLQ + row] = lrun;
}

// -------------------- K4: proj GEMM + 4-way sum-combine: ADb(B,C,T) bf16 -------------
__global__ __launch_bounds__(256) void proj_kernel(
    const u16* __restrict__ XP, const float* __restrict__ ML,
    const float* __restrict__ Wp, const float* __restrict__ gate,
    u16* __restrict__ ADb)
{
    __shared__ u16 xa_lds[64 * 64];      // [t][d], swzA
    const int tid = threadIdx.x;
    const int lane = tid & 63, w = tid >> 6, g = lane >> 4, q15 = lane & 15;
    const int b = blockIdx.x >> 5, t0 = (blockIdx.x & 31) * 64;
    char* xl = (char*)xa_lds;
    // stage XA tile (64t x 64d): max-free combine = plain sum of bf16 partials
    {
        const size_t q = (size_t)b * TT + t0 + (tid >> 2);
        const float inv = 1.0f / (ML[q] + ML[MLQ + q] + ML[2 * MLQ + q] + ML[3 * MLQ + q]);
        const int dq = (tid & 3) * 16;
        float c[16];
        #pragma unroll
        for (int e = 0; e < 16; ++e) c[e] = 0.f;
        #pragma unroll
        for (int h = 0; h < 4; ++h) {
            const u16* pr = XP + (size_t)h * XPH + q * DK + dq;
            uint4 u0 = *(const uint4*)(pr);
            uint4 u1 = *(const uint4*)(pr + 8);
            u32 uv[8] = {u0.x, u0.y, u0.z, u0.w, u1.x, u1.y, u1.z, u1.w};
            #pragma unroll
            for (int k = 0; k < 8; ++k) {
                c[2 * k]     += __builtin_bit_cast(float, uv[k] << 16);
                c[2 * k + 1] += __builtin_bit_cast(float, uv[k] & 0xFFFF0000u);
            }
        }
        #pragma unroll
        for (int e = 0; e < 16; ++e) c[e] *= inv;
        u32 base = (u32)((tid >> 2) * 128 + (tid & 3) * 32);
        uint4 w0 = {pk2(c[0], c[1]), pk2(c[2], c[3]), pk2(c[4], c[5]), pk2(c[6], c[7])};
        uint4 w1 = {pk2(c[8], c[9]), pk2(c[10], c[11]), pk2(c[12], c[13]), pk2(c[14], c[15])};
        *(uint4*)(xl + swzA(base))      = w0;
        *(uint4*)(xl + swzA(base + 16)) = w1;
    }
    short8 af[4][2];
    #pragma unroll
    for (int ci = 0; ci < 4; ++ci) {
        const float* wr = Wp + (size_t)(16 * (4 * w + ci) + q15) * DK + 8 * g;
        #pragma unroll
        for (int kw = 0; kw < 2; ++kw) {
            float4 a = *(const float4*)(wr + kw * 32);
            float4 c = *(const float4*)(wr + kw * 32 + 4);
            short8 s;
            s[0] = (short)f2bf(a.x); s[1] = (short)f2bf(a.y);
            s[2] = (short)f2bf(a.z); s[3] = (short)f2bf(a.w);
            s[4] = (short)f2bf(c.x); s[5] = (short)f2bf(c.y);
            s[6] = (short)f2bf(c.z); s[7] = (short)f2bf(c.w);
            af[ci][kw] = s;
        }
    }
    __syncthreads();
    const f32x4 zf = {0.f, 0.f, 0.f, 0.f};
    f32x4 acc[4][4];
    #pragma unroll
    for (int ci = 0; ci < 4; ++ci)
        #pragma unroll
        for (int tt = 0; tt < 4; ++tt) acc[ci][tt] = zf;
    #pragma unroll
    for (int tt = 0; tt < 4; ++tt)
        #pragma unroll
        for (int kw = 0; kw < 2; ++kw) {
            short8 bf = *(const short8*)(xl +
                swzA((u32)((16 * tt + q15) * 128 + kw * 64 + 16 * g)));
            #pragma unroll
            for (int ci = 0; ci < 4; ++ci)
                acc[ci][tt] = __builtin_amdgcn_mfma_f32_16x16x32_bf16(af[ci][kw], bf, acc[ci][tt], 0, 0, 0);
        }
    const float sg = 1.0f / (1.0f + __expf(-gate[0]));
    u16* ad = ADb + (size_t)b * (CC * TT);
    #pragma unroll
    for (int ci = 0; ci < 4; ++ci)
        #pragma unroll
        for (int tt = 0; tt < 4; ++tt) {
            int t = t0 + 16 * tt + q15;
            #pragma unroll
            for (int r = 0; r < 4; ++r) {
                int c = 16 * (4 * w + ci) + 4 * g + r;
                ad[(size_t)c * TT + t] = f2bf(sg * acc[ci][tt][r]);
            }
        }
}

// -------------------- K5: residual broadcast-add: out = x + ADb[b,c,t] over V --------
// REVERSED block order (consume pool's L3-resident x-tail first) + NON-TEMPORAL
// x loads / out stores via ext-vector f32x4 (builtin requires clang vector type).
__global__ void final_kernel(const float* __restrict__ x, const u16* __restrict__ ADb,
                             float* __restrict__ out) {
    __shared__ float ad_lds[TT];
    const int tid = threadIdx.x;
    const int blk = (BB * CC - 1) - blockIdx.x;      // reverse order
    {
        uint4 v = ((const uint4*)(ADb + (size_t)blk * TT))[tid];
        u32 ww[4] = {v.x, v.y, v.z, v.w};
        #pragma unroll
        for (int k = 0; k < 4; ++k) {
            float lo = __builtin_bit_cast(float, ww[k] << 16);
            float hi = __builtin_bit_cast(float, ww[k] & 0xFFFF0000u);
            float2 pr = {lo, hi};
            *(float2*)&ad_lds[8 * tid + 2 * k] = pr;
        }
    }
    __syncthreads();
    const size_t base = (size_t)blk * (TT * VV);
    #pragma unroll 2
    for (int it = 0; it < (TT * VV) / (256 * 4); ++it) {
        int e = (it * 256 + tid) * 4;
        f32x4 xv = __builtin_nontemporal_load((const f32x4*)&x[base + e]);
        f32x4 ov;
        ov.x = xv.x + ad_lds[(e) / 25];
        ov.y = xv.y + ad_lds[(e + 1) / 25];
        ov.z = xv.z + ad_lds[(e + 2) / 25];
        ov.w = xv.w + ad_lds[(e + 3) / 25];
        __builtin_nontemporal_store(ov, (f32x4*)&out[base + e]);
    }
}

extern "C" void kernel_launch(void* const* d_in, const int* in_sizes, int n_in,
                              void* d_out, int out_size, void* d_ws, size_t ws_size,
                              hipStream_t stream) {
    const float* x    = (const float*)d_in[0];
    const float* Wq   = (const float*)d_in[1];
    const float* Wk   = (const float*)d_in[2];
    const float* Wv   = (const float*)d_in[3];
    const float* Wp   = (const float*)d_in[4];
    const float* gate = (const float*)d_in[5];
    float* out = (float*)d_out;
    float* ws = (float*)d_ws;

    // ws layout (float offsets):
    //   p0b  @ 0         (1,048,576 floats = B*C*T u16)
    //   ADb  @ 1048576   (2,097,152 floats = B*C*T u16)
    //   XPb  @ 3145728   (4 x 1,048,576 u16 = 2,097,152 floats)
    //   ML   @ 5242880   (65,536 floats)
    //   QR   @ 5308416   (524,288 floats = B*T*DK u16, row-major)
    //   KT   @ 5832704   (524,288)
    //   VT   @ 6356992   (524,288)  ends 6,881,280 floats = 26.25 MB
    u16*   p0b = (u16*)(ws);
    u16*   ADb = (u16*)(ws + 1048576);
    u16*   XPb = (u16*)(ws + 3145728);
    float* MLb = ws + 5242880;
    u16*   QR  = (u16*)(ws + 5308416);
    u16*   KT  = (u16*)(ws + 5832704);
    u16*   VT  = (u16*)(ws + 6356992);

    pool_kernel<<<2048, 256, 0, stream>>>(x, p0b);                       // x -> (B,C,T) bf16
    qkv_gemm<<<256, 256, 0, stream>>>(p0b, Wq, Wk, Wv, QR, KT, VT);      // -> Q row, K/V col
    flash_kernel<<<1024, 256, 0, stream>>>(QR, KT, VT, XPb, MLb);        // -> bf16 partials x4
    proj_kernel<<<256, 256, 0, stream>>>(XPb, MLb, Wp, gate, ADb);       // sum-combine + GEMM
    final_kernel<<<2048, 256, 0, stream>>>(x, ADb, out);
}

// Round 11
// 254.146 us; speedup vs baseline: 1.4238x; 1.0070x over previous
//
#include <hip/hip_runtime.h>
#include <math.h>

// Problem constants (B, C, T, V, d_k) = (8, 256, 2048, 25, 64)
#define BB 8
#define CC 256
#define TT 2048
#define VV 25
#define DK 64
#define XPH 1048576   // B*T*DK u16 elements per KV-split quarter
#define MLQ 16384     // B*T floats (l only; max-free softmax) per quarter

typedef unsigned short u16;
typedef unsigned int u32;
typedef float f32x4 __attribute__((ext_vector_type(4)));
typedef short short8 __attribute__((ext_vector_type(8)));

__device__ __forceinline__ u16 f2bf(float x) {
    u32 u = __builtin_bit_cast(u32, x);
    u32 r = (u + 0x7FFFu + ((u >> 16) & 1u)) >> 16;   // RNE
    return (u16)r;
}
__device__ __forceinline__ u32 pk2(float a, float b) {
    return (u32)f2bf(a) | ((u32)f2bf(b) << 16);
}
// HW packed cvt (T12, m214v22): D.lo = bf16(S0), D.hi = bf16(S1), RNE
__device__ __forceinline__ u32 cvtpk(float a, float b) {
    u32 r;
    asm("v_cvt_pk_bf16_f32 %0, %1, %2" : "=v"(r) : "v"(a), "v"(b));
    return r;
}

// XOR swizzles (T2). Row-stride-128B tiles: swzA f(row)=row&7. swzX: 512B rows.
__device__ __forceinline__ u32 swzA(u32 byte) {
    return byte ^ (((byte >> 7) & 7u) << 4);
}
__device__ __forceinline__ u32 swzX(u32 byte) {
    return byte ^ (((byte >> 9) & 7u) << 4);
}

// -------------------- K1: pool over V: x (B,C,T,V) -> p0 (B,C,T) bf16 ----------------
// Wave-local LDS staging: each wave owns a 12.8 KB region (128 rows x 25),
// no __syncthreads anywhere — ordering is in-wave lgkmcnt only.
__global__ __launch_bounds__(256) void pool_kernel(const float* __restrict__ x,
                                                   u16* __restrict__ p0) {
    __shared__ float lds[4][128 * VV];
    const int lane = threadIdx.x & 63, w = threadIdx.x >> 6;
    float* buf = lds[w];
    const int ch0 = (blockIdx.x * 4 + w) * 4;
    #pragma unroll 1
    for (int it = 0; it < 4; ++it) {
        const long long ch = ch0 + it;
        const uint2* xu = (const uint2*)(x + ch * (128LL * VV));
        #pragma unroll
        for (int j = 0; j < VV; ++j)
            *(uint2*)&buf[2 * (lane + 64 * j)] = xu[lane + 64 * j];
        float s0 = 0.f, s1 = 0.f;
        #pragma unroll
        for (int j = 0; j < VV; ++j) {
            s0 += buf[50 * lane + j];
            s1 += buf[50 * lane + VV + j];
        }
        *(u32*)&p0[ch * 128 + 2 * lane] = pk2(s0 * (1.0f / 25.0f),
                                              s1 * (1.0f / 25.0f));
    }
}

// -------------------- K2: fused QKV GEMM: QR/KR (B,T,64) row; VT (B,64,T) col --------
// 256 blocks = 8b x 32 t-chunks(64). p0 is bf16: stage = bit-merge only.
// Q pre-scaled by (1/8)*log2(e). Q AND K row-major (packed uint2 epilogue;
// flash stages both as direct copies).
__global__ __launch_bounds__(256) void qkv_gemm(
    const u16* __restrict__ p0, const float* __restrict__ Wq,
    const float* __restrict__ Wk, const float* __restrict__ Wv,
    u16* __restrict__ QR, u16* __restrict__ KR, u16* __restrict__ VT)
{
    __shared__ u16 xlds[64 * 256];       // [t][c], swzX
    const int tid = threadIdx.x;
    const int lane = tid & 63, w = tid >> 6, g = lane >> 4, q15 = lane & 15;
    const int b = blockIdx.x >> 5, t0 = (blockIdx.x & 31) * 64;
    const u16* p0b = p0 + (size_t)b * (CC * TT);

    // stage x_t^T tile (bf16 in, [t][c] packed pairs out)
    const int c0 = (tid & 127) * 2, th = tid >> 7;
    char* xl = (char*)xlds;
    {
        const u16* r0p = p0b + (size_t)c0 * TT + t0 + th * 32;
        const u16* r1p = r0p + TT;
        #pragma unroll
        for (int j = 0; j < 4; ++j) {
            uint4 a = ((const uint4*)r0p)[j];    // 8 t's of row c0
            uint4 bq = ((const uint4*)r1p)[j];   // 8 t's of row c0+1
            u32 av[4] = {a.x, a.y, a.z, a.w};
            u32 bv[4] = {bq.x, bq.y, bq.z, bq.w};
            #pragma unroll
            for (int e = 0; e < 4; ++e) {
                int tb = th * 32 + j * 8 + e * 2;
                u32 w0 = (av[e] & 0xFFFFu) | (bv[e] << 16);
                u32 w1 = (av[e] >> 16) | (bv[e] & 0xFFFF0000u);
                *(u32*)(xl + swzX((u32)(tb * 512 + c0 * 2)))       = w0;
                *(u32*)(xl + swzX((u32)((tb + 1) * 512 + c0 * 2))) = w1;
            }
        }
    }
    short8 af[3][8];
    const float* Wmats[3] = {Wq, Wk, Wv};
    #pragma unroll
    for (int m = 0; m < 3; ++m) {
        const float* wr = Wmats[m] + (16 * w + q15) * 256 + 8 * g;
        const float scale = (m == 0) ? 0.125f * 1.44269504089f : 1.0f;  // fold log2(e)
        #pragma unroll
        for (int kw = 0; kw < 8; ++kw) {
            float4 a = *(const float4*)(wr + kw * 32);
            float4 c = *(const float4*)(wr + kw * 32 + 4);
            short8 s;
            s[0] = (short)f2bf(a.x * scale); s[1] = (short)f2bf(a.y * scale);
            s[2] = (short)f2bf(a.z * scale); s[3] = (short)f2bf(a.w * scale);
            s[4] = (short)f2bf(c.x * scale); s[5] = (short)f2bf(c.y * scale);
            s[6] = (short)f2bf(c.z * scale); s[7] = (short)f2bf(c.w * scale);
            af[m][kw] = s;
        }
    }
    __syncthreads();
    const f32x4 zf = {0.f, 0.f, 0.f, 0.f};
    f32x4 acc[3][4];
    #pragma unroll
    for (int m = 0; m < 3; ++m)
        #pragma unroll
        for (int tt = 0; tt < 4; ++tt) acc[m][tt] = zf;
    #pragma unroll
    for (int tt = 0; tt < 4; ++tt)
        #pragma unroll
        for (int kw = 0; kw < 8; ++kw) {
            short8 bf = *(const short8*)(xl +
                swzX((u32)((16 * tt + q15) * 512 + kw * 64 + 16 * g)));
            acc[0][tt] = __builtin_amdgcn_mfma_f32_16x16x32_bf16(af[0][kw], bf, acc[0][tt], 0, 0, 0);
            acc[1][tt] = __builtin_amdgcn_mfma_f32_16x16x32_bf16(af[1][kw], bf, acc[1][tt], 0, 0, 0);
            acc[2][tt] = __builtin_amdgcn_mfma_f32_16x16x32_bf16(af[2][kw], bf, acc[2][tt], 0, 0, 0);
        }
    u16* qo = QR + (size_t)b * (TT * DK);
    u16* ko = KR + (size_t)b * (TT * DK);
    u16* vo = VT + (size_t)b * (DK * TT);
    #pragma unroll
    for (int tt = 0; tt < 4; ++tt) {
        int t = t0 + 16 * tt + q15;
        // Q,K row-major: 4 consecutive d at d0 = 16w+4g -> one uint2 each
        uint2 qw, kw2;
        qw.x  = pk2(acc[0][tt][0], acc[0][tt][1]);
        qw.y  = pk2(acc[0][tt][2], acc[0][tt][3]);
        kw2.x = pk2(acc[1][tt][0], acc[1][tt][1]);
        kw2.y = pk2(acc[1][tt][2], acc[1][tt][3]);
        *(uint2*)&qo[(size_t)t * DK + 16 * w + 4 * g] = qw;
        *(uint2*)&ko[(size_t)t * DK + 16 * w + 4 * g] = kw2;
        #pragma unroll
        for (int r = 0; r < 4; ++r) {
            int d = 16 * w + 4 * g + r;
            vo[(size_t)d * TT + t] = f2bf(acc[2][tt][r]);
        }
    }
}

// -------------------- K3: flash attention, KV-split x4, single-buffer (6 blk/CU) -----
// K now row-major: staging is a direct swzA copy (same as V) — no transpose-
// pack VALU. Max-free exp2 softmax (scale folded in Q); bf16 partials out.
__global__ __launch_bounds__(256) void flash_kernel(
    const u16* __restrict__ QR, const u16* __restrict__ KR,
    const u16* __restrict__ VT, u16* __restrict__ XP, float* __restrict__ ML)
{
    __shared__ u16 k_lds[4096];      // [64 kv][64 d], swzA (direct copy of K rows)
    __shared__ u16 v_lds[4096];      // [64 d][64 kv], swzA (direct copy of V^T)
    __shared__ u16 p_lds[4][1024];   // per-wave [16 q][64 kv], swzA

    const int tid  = threadIdx.x;
    const int lane = tid & 63;
    const int w    = tid >> 6;
    const int g    = lane >> 4;
    const int q15  = lane & 15;

    const int bi   = blockIdx.x & 7;             // XCD-aligned: batch per XCD
    const int rest = blockIdx.x >> 3;
    const int qt   = rest & 31;
    const int quar = rest >> 5;                  // KV quarter 0..3
    const int q0 = qt * 64 + w * 16;
    const size_t boff = (size_t)bi * (DK * TT);

    const u16* Kb = KR + boff;                   // row-major (T,64)
    const u16* Vb = VT + boff;                   // col-major (64,T)

    // Q fragment: lane holds Q[q0+q15][8g+e (+32)] — two 16B loads (row-major QR)
    short8 qf0, qf1;
    {
        const u16* qr = QR + boff + (size_t)(q0 + q15) * DK + 8 * g;
        qf0 = *(const short8*)(qr);
        qf1 = *(const short8*)(qr + 32);
    }

    float lrun = 0.f;                            // per-lane partial sum
    const f32x4 zf = {0.f, 0.f, 0.f, 0.f};
    f32x4 oacc[4];
    #pragma unroll
    for (int i = 0; i < 4; ++i) oacc[i] = zf;

    const int s2 = tid >> 3, c8 = tid & 7;       // row tid>>3, 16B-col tid&7
    const int kv0 = quar * 512;
    char* kl = (char*)k_lds;
    char* vl = (char*)v_lds;
    char* pl = (char*)p_lds[w];

    // K rows (kv, 64d) contiguous; V^T rows (d, 64kv) at column kv0
    uint4 ka  = *(const uint4*)(Kb + (size_t)(kv0 + s2) * DK + c8 * 8);
    uint4 kb2 = *(const uint4*)(Kb + (size_t)(kv0 + s2 + 32) * DK + c8 * 8);
    uint4 va  = *(const uint4*)(Vb + (size_t)s2 * TT + kv0 + c8 * 8);
    uint4 vb2 = *(const uint4*)(Vb + (size_t)(s2 + 32) * TT + kv0 + c8 * 8);

    for (int it = 0; it < 8; ++it) {
        if (it) __syncthreads();                 // prev tile fully consumed
        // ---- K,V: direct copies -> [row][64] swzA ----
        *(uint4*)(kl + swzA((u32)(tid * 16)))        = ka;
        *(uint4*)(kl + swzA((u32)(tid * 16 + 4096))) = kb2;
        *(uint4*)(vl + swzA((u32)(tid * 16)))        = va;
        *(uint4*)(vl + swzA((u32)(tid * 16 + 4096))) = vb2;
        __syncthreads();
        // ---- issue next tile's global loads (hide under compute) ----
        if (it + 1 < 8) {
            const int kb = kv0 + (it + 1) * 64;
            ka  = *(const uint4*)(Kb + (size_t)(kb + s2) * DK + c8 * 8);
            kb2 = *(const uint4*)(Kb + (size_t)(kb + s2 + 32) * DK + c8 * 8);
            va  = *(const uint4*)(Vb + (size_t)s2 * TT + kb + c8 * 8);
            vb2 = *(const uint4*)(Vb + (size_t)(s2 + 32) * TT + kb + c8 * 8);
        }
        // ---- QK^T (swapped): S^T[kv][q] = K.Q^T ----
        f32x4 sa[4];
        __builtin_amdgcn_s_setprio(1);
        #pragma unroll
        for (int f = 0; f < 4; ++f) {
            short8 k0 = *(const short8*)(kl + swzA((u32)((16 * f + q15) * 128 + 16 * g)));
            short8 k1 = *(const short8*)(kl + swzA((u32)((16 * f + q15) * 128 + 64 + 16 * g)));
            f32x4 t = __builtin_amdgcn_mfma_f32_16x16x32_bf16(k0, qf0, zf, 0, 0, 0);
            sa[f]   = __builtin_amdgcn_mfma_f32_16x16x32_bf16(k1, qf1, t, 0, 0, 0);
        }
        __builtin_amdgcn_s_setprio(0);
        // ---- max-free softmax: p = exp2(s), lane-local l accumulation ----
        float p[4][4];
        #pragma unroll
        for (int f = 0; f < 4; ++f)
            #pragma unroll
            for (int r = 0; r < 4; ++r) {
                p[f][r] = exp2f(sa[f][r]);       // scale folded in Q at qkv time
                lrun += p[f][r];
            }
        // ---- P -> bf16 (HW cvt_pk) -> per-wave LDS [q][kv] ----
        #pragma unroll
        for (int f = 0; f < 4; ++f) {
            uint2 pw;
            pw.x = cvtpk(p[f][0], p[f][1]);
            pw.y = cvtpk(p[f][2], p[f][3]);
            *(uint2*)(pl + swzA((u32)(q15 * 128 + f * 32 + g * 8))) = pw;
        }
        asm volatile("s_waitcnt lgkmcnt(0)" ::: "memory");
        __builtin_amdgcn_sched_barrier(0);        // rule #18: pin MFMA after wait
        // ---- PV: O^T[d][q] += V^T . P^T ----
        short8 pf0 = *(const short8*)(pl + swzA((u32)(q15 * 128 + 16 * g)));
        short8 pf1 = *(const short8*)(pl + swzA((u32)(q15 * 128 + 64 + 16 * g)));
        __builtin_amdgcn_s_setprio(1);
        #pragma unroll
        for (int dt = 0; dt < 4; ++dt) {
            short8 v0 = *(const short8*)(vl + swzA((u32)((16 * dt + q15) * 128 + 16 * g)));
            short8 v1 = *(const short8*)(vl + swzA((u32)((16 * dt + q15) * 128 + 64 + 16 * g)));
            oacc[dt] = __builtin_amdgcn_mfma_f32_16x16x32_bf16(v0, pf0, oacc[dt], 0, 0, 0);
            oacc[dt] = __builtin_amdgcn_mfma_f32_16x16x32_bf16(v1, pf1, oacc[dt], 0, 0, 0);
        }
        __builtin_amdgcn_s_setprio(0);
    }
    // ---- epilogue: bf16 raw partial O + fp32 l (single cross-lane reduce) ----
    lrun += __shfl_xor(lrun, 16);
    lrun += __shfl_xor(lrun, 32);
    const size_t row = (size_t)bi * TT + q0 + q15;
    u16* xo = XP + (size_t)quar * XPH + row * DK;
    #pragma unroll
    for (int dt = 0; dt < 4; ++dt) {
        uint2 o;
        o.x = cvtpk(oacc[dt][0], oacc[dt][1]);
        o.y = cvtpk(oacc[dt][2], oacc[dt][3]);
        *(uint2*)(xo + 16 * dt + 4 * g) = o;
    }
    if (g == 0)
        ML[(size_t)quar * MLQ + row] = lrun;
}

// -------------------- K4: proj GEMM + 4-way sum-combine: ADb(B,C,T) bf16 -------------
__global__ __launch_bounds__(256) void proj_kernel(
    const u16* __restrict__ XP, const float* __restrict__ ML,
    const float* __restrict__ Wp, const float* __restrict__ gate,
    u16* __restrict__ ADb)
{
    __shared__ u16 xa_lds[64 * 64];      // [t][d], swzA
    const int tid = threadIdx.x;
    const int lane = tid & 63, w = tid >> 6, g = lane >> 4, q15 = lane & 15;
    const int b = blockIdx.x >> 5, t0 = (blockIdx.x & 31) * 64;
    char* xl = (char*)xa_lds;
    // stage XA tile (64t x 64d): max-free combine = plain sum of bf16 partials
    {
        const size_t q = (size_t)b * TT + t0 + (tid >> 2);
        const float inv = 1.0f / (ML[q] + ML[MLQ + q] + ML[2 * MLQ + q] + ML[3 * MLQ + q]);
        const int dq = (tid & 3) * 16;
        float c[16];
        #pragma unroll
        for (int e = 0; e < 16; ++e) c[e] = 0.f;
        #pragma unroll
        for (int h = 0; h < 4; ++h) {
            const u16* pr = XP + (size_t)h * XPH + q * DK + dq;
            uint4 u0 = *(const uint4*)(pr);
            uint4 u1 = *(const uint4*)(pr + 8);
            u32 uv[8] = {u0.x, u0.y, u0.z, u0.w, u1.x, u1.y, u1.z, u1.w};
            #pragma unroll
            for (int k = 0; k < 8; ++k) {
                c[2 * k]     += __builtin_bit_cast(float, uv[k] << 16);
                c[2 * k + 1] += __builtin_bit_cast(float, uv[k] & 0xFFFF0000u);
            }
        }
        #pragma unroll
        for (int e = 0; e < 16; ++e) c[e] *= inv;
        u32 base = (u32)((tid >> 2) * 128 + (tid & 3) * 32);
        uint4 w0 = {pk2(c[0], c[1]), pk2(c[2], c[3]), pk2(c[4], c[5]), pk2(c[6], c[7])};
        uint4 w1 = {pk2(c[8], c[9]), pk2(c[10], c[11]), pk2(c[12], c[13]), pk2(c[14], c[15])};
        *(uint4*)(xl + swzA(base))      = w0;
        *(uint4*)(xl + swzA(base + 16)) = w1;
    }
    short8 af[4][2];
    #pragma unroll
    for (int ci = 0; ci < 4; ++ci) {
        const float* wr = Wp + (size_t)(16 * (4 * w + ci) + q15) * DK + 8 * g;
        #pragma unroll
        for (int kw = 0; kw < 2; ++kw) {
            float4 a = *(const float4*)(wr + kw * 32);
            float4 c = *(const float4*)(wr + kw * 32 + 4);
            short8 s;
            s[0] = (short)f2bf(a.x); s[1] = (short)f2bf(a.y);
            s[2] = (short)f2bf(a.z); s[3] = (short)f2bf(a.w);
            s[4] = (short)f2bf(c.x); s[5] = (short)f2bf(c.y);
            s[6] = (short)f2bf(c.z); s[7] = (short)f2bf(c.w);
            af[ci][kw] = s;
        }
    }
    __syncthreads();
    const f32x4 zf = {0.f, 0.f, 0.f, 0.f};
    f32x4 acc[4][4];
    #pragma unroll
    for (int ci = 0; ci < 4; ++ci)
        #pragma unroll
        for (int tt = 0; tt < 4; ++tt) acc[ci][tt] = zf;
    #pragma unroll
    for (int tt = 0; tt < 4; ++tt)
        #pragma unroll
        for (int kw = 0; kw < 2; ++kw) {
            short8 bf = *(const short8*)(xl +
                swzA((u32)((16 * tt + q15) * 128 + kw * 64 + 16 * g)));
            #pragma unroll
            for (int ci = 0; ci < 4; ++ci)
                acc[ci][tt] = __builtin_amdgcn_mfma_f32_16x16x32_bf16(af[ci][kw], bf, acc[ci][tt], 0, 0, 0);
        }
    const float sg = 1.0f / (1.0f + __expf(-gate[0]));
    u16* ad = ADb + (size_t)b * (CC * TT);
    #pragma unroll
    for (int ci = 0; ci < 4; ++ci)
        #pragma unroll
        for (int tt = 0; tt < 4; ++tt) {
            int t = t0 + 16 * tt + q15;
            #pragma unroll
            for (int r = 0; r < 4; ++r) {
                int c = 16 * (4 * w + ci) + 4 * g + r;
                ad[(size_t)c * TT + t] = f2bf(sg * acc[ci][tt][r]);
            }
        }
}

// -------------------- K5: residual broadcast-add: out = x + ADb[b,c,t] over V --------
// REVERSED block order (consume pool's L3-resident x-tail first). NON-TEMPORAL
// out stores kill RFO/write-allocate (R10's -65 µs — do not remove); nt x loads
// avoid re-allocating dead lines.
__global__ void final_kernel(const float* __restrict__ x, const u16* __restrict__ ADb,
                             float* __restrict__ out) {
    __shared__ float ad_lds[TT];
    const int tid = threadIdx.x;
    const int blk = (BB * CC - 1) - blockIdx.x;      // reverse order
    {
        uint4 v = ((const uint4*)(ADb + (size_t)blk * TT))[tid];
        u32 ww[4] = {v.x, v.y, v.z, v.w};
        #pragma unroll
        for (int k = 0; k < 4; ++k) {
            float lo = __builtin_bit_cast(float, ww[k] << 16);
            float hi = __builtin_bit_cast(float, ww[k] & 0xFFFF0000u);
            float2 pr = {lo, hi};
            *(float2*)&ad_lds[8 * tid + 2 * k] = pr;
        }
    }
    __syncthreads();
    const size_t base = (size_t)blk * (TT * VV);
    #pragma unroll 2
    for (int it = 0; it < (TT * VV) / (256 * 4); ++it) {
        int e = (it * 256 + tid) * 4;
        f32x4 xv = __builtin_nontemporal_load((const f32x4*)&x[base + e]);
        f32x4 ov;
        ov.x = xv.x + ad_lds[(e) / 25];
        ov.y = xv.y + ad_lds[(e + 1) / 25];
        ov.z = xv.z + ad_lds[(e + 2) / 25];
        ov.w = xv.w + ad_lds[(e + 3) / 25];
        __builtin_nontemporal_store(ov, (f32x4*)&out[base + e]);
    }
}

extern "C" void kernel_launch(void* const* d_in, const int* in_sizes, int n_in,
                              void* d_out, int out_size, void* d_ws, size_t ws_size,
                              hipStream_t stream) {
    const float* x    = (const float*)d_in[0];
    const float* Wq   = (const float*)d_in[1];
    const float* Wk   = (const float*)d_in[2];
    const float* Wv   = (const float*)d_in[3];
    const float* Wp   = (const float*)d_in[4];
    const float* gate = (const float*)d_in[5];
    float* out = (float*)d_out;
    float* ws = (float*)d_ws;

    // ws layout (float offsets):
    //   p0b  @ 0         (1,048,576 floats = B*C*T u16)
    //   ADb  @ 1048576   (2,097,152 floats = B*C*T u16)
    //   XPb  @ 3145728   (4 x 1,048,576 u16 = 2,097,152 floats)
    //   ML   @ 5242880   (65,536 floats)
    //   QR   @ 5308416   (524,288 floats = B*T*DK u16, row-major)
    //   KR   @ 5832704   (524,288, row-major)
    //   VT   @ 6356992   (524,288, col-major)  ends 6,881,280 floats = 26.25 MB
    u16*   p0b = (u16*)(ws);
    u16*   ADb = (u16*)(ws + 1048576);
    u16*   XPb = (u16*)(ws + 3145728);
    float* MLb = ws + 5242880;
    u16*   QR  = (u16*)(ws + 5308416);
    u16*   KR  = (u16*)(ws + 5832704);
    u16*   VT  = (u16*)(ws + 6356992);

    pool_kernel<<<2048, 256, 0, stream>>>(x, p0b);                       // x -> (B,C,T) bf16
    qkv_gemm<<<256, 256, 0, stream>>>(p0b, Wq, Wk, Wv, QR, KR, VT);      // -> Q,K row; V col
    flash_kernel<<<1024, 256, 0, stream>>>(QR, KR, VT, XPb, MLb);        // -> bf16 partials x4
    proj_kernel<<<256, 256, 0, stream>>>(XPb, MLb, Wp, gate, ADb);       // sum-combine + GEMM
    final_kernel<<<2048, 256, 0, stream>>>(x, ADb, out);
}